// Round 5
// baseline (46.628 us; speedup 1.0000x reference)
//
#include <hip/hip_runtime.h>
#include <hip/hip_bf16.h>

#define N_NODES 65536
#define NUM_G   64
#define GSIZE   1024
#define DIM     64

using frag_ab = __attribute__((ext_vector_type(8))) short;   // 8 bf16 (4 VGPRs)
using f32x4   = __attribute__((ext_vector_type(4))) float;   // 4 fp32 accum

__device__ __forceinline__ unsigned short f2bf(float x) {
    union { float f; unsigned int u; } v; v.f = x;
    unsigned int r = v.u + 0x7FFFu + ((v.u >> 16) & 1u);   // RNE
    return (unsigned short)(r >> 16);
}

// Kernel 1: fp32 row-normalize z1,z2 -> bf16 copies; pos = (z1n . z2n) * inv_t (fp32).
__global__ __launch_bounds__(256) void normalize_k(
    const float* __restrict__ z1, const float* __restrict__ z2,
    unsigned short* __restrict__ z1n, unsigned short* __restrict__ z2n,
    float* __restrict__ pos)
{
    int tid = threadIdx.x;
    int row = blockIdx.x * 16 + (tid >> 4);
    int l4  = tid & 15;
    float4 v1 = *((const float4*)(z1 + (size_t)row * DIM) + l4);
    float4 v2 = *((const float4*)(z2 + (size_t)row * DIM) + l4);
    float ss1 = v1.x*v1.x + v1.y*v1.y + v1.z*v1.z + v1.w*v1.w;
    float ss2 = v2.x*v2.x + v2.y*v2.y + v2.z*v2.z + v2.w*v2.w;
    float dt  = v1.x*v2.x + v1.y*v2.y + v1.z*v2.z + v1.w*v2.w;
    #pragma unroll
    for (int m = 1; m < 16; m <<= 1) {
        ss1 += __shfl_xor(ss1, m);
        ss2 += __shfl_xor(ss2, m);
        dt  += __shfl_xor(dt,  m);
    }
    float in1 = 1.0f / sqrtf(ss1);
    float in2 = 1.0f / sqrtf(ss2);
    ushort4 o1, o2;
    o1.x = f2bf(v1.x*in1); o1.y = f2bf(v1.y*in1); o1.z = f2bf(v1.z*in1); o1.w = f2bf(v1.w*in1);
    o2.x = f2bf(v2.x*in2); o2.y = f2bf(v2.y*in2); o2.z = f2bf(v2.z*in2); o2.w = f2bf(v2.w*in2);
    *((ushort4*)(z1n + (size_t)row * DIM) + l4) = o1;
    *((ushort4*)(z2n + (size_t)row * DIM) + l4) = o2;
    if (l4 == 0) pos[row] = dt * in1 * in2 * 2.0f;   // inv_t = 2
}

// Kernel 2: NO LDS staging, NO main-loop barriers. Each wave holds all 128 block
// rows of z1 in registers (A = 64 VGPRs) and streams 512 of the 2048 virtual
// columns [z2 | z1] straight from L2 (graph's 512KB is L2-resident; XCD swizzle
// clusters a graph's 8 blocks on one XCD). Next-tile register prefetch.
// Per-wave partial row-sums merged once through a 2KB LDS array at the end.
__global__ __launch_bounds__(256, 3) void grace_main_k(
    const unsigned short* __restrict__ z1n,
    const unsigned short* __restrict__ z2n,
    const float* __restrict__ pos,
    float* __restrict__ partials)
{
    __shared__ float sums[4][128];   // per-wave partial row sums
    __shared__ float red[4];

    int tid = threadIdx.x;
    int n = blockIdx.x;
    int g = (n & 7) + 8 * (n >> 6);   // all 8 blocks of a graph share XCD (n%8 model)
    int stripe = (n >> 3) & 7;
    int w = tid >> 6, l = tid & 63;
    const unsigned short* z1g = z1n + (size_t)g * GSIZE * DIM;
    const unsigned short* z2g = z2n + (size_t)g * GSIZE * DIM;
    int rowBase = stripe * 128;

    // A fragments: all 128 rows, 8 tiles x 2 K-halves. A[rt][h][lane] = z1[row][k]
    // row = rowBase + rt*16 + (l&15), k = h*32 + (l>>4)*8 ..+8
    int ar = l & 15, ak = (l >> 4) * 8;
    frag_ab A[8][2];
    #pragma unroll
    for (int rt = 0; rt < 8; ++rt) {
        const unsigned short* p = z1g + (rowBase + rt * 16 + ar) * DIM + ak;
        A[rt][0] = *(const frag_ab*)(p);
        A[rt][1] = *(const frag_ab*)(p + 32);
    }

    float expacc[8][4] = {};   // static indexing only (fully unrolled loops)

    // Column stream: wave w covers virtual cols [w*512, w*512+512) of [z2 | z1].
    // Wave-uniform matrix choice: w<2 -> z2, w>=2 -> z1; local col base (w&1)*512.
    const unsigned short* sb =
        ((w < 2) ? z2g : z1g) + ((w & 1) * 512 + ar) * DIM + ak;

    const float K1 = 2.8853900817779268f;   // 2 * log2(e)   (inv_t=2 folded)
    const float K0 = -2.8853900817779268f;  // -2 * log2(e)  (fixed shift m=2)

    frag_ab b0 = *(const frag_ab*)(sb);
    frag_ab b1 = *(const frag_ab*)(sb + 32);
    sb += 16 * DIM;

    #pragma unroll 1
    for (int t = 0; t < 32; ++t) {
        frag_ab nb0, nb1;
        if (t < 31) {                        // issue next tile's loads early
            nb0 = *(const frag_ab*)(sb);
            nb1 = *(const frag_ab*)(sb + 32);
            sb += 16 * DIM;
        }
        #pragma unroll
        for (int rt = 0; rt < 8; ++rt) {
            f32x4 z = {0.f, 0.f, 0.f, 0.f};
            f32x4 c = __builtin_amdgcn_mfma_f32_16x16x32_bf16(A[rt][0], b0, z, 0, 0, 0);
            c = __builtin_amdgcn_mfma_f32_16x16x32_bf16(A[rt][1], b1, c, 0, 0, 0);
            #pragma unroll
            for (int r = 0; r < 4; ++r)
                expacc[rt][r] += __builtin_amdgcn_exp2f(fmaf(c[r], K1, K0));
        }
        if (t < 31) { b0 = nb0; b1 = nb1; }
    }

    // Reduce C cols (low-4 lane bits), publish per-wave row sums.
    // C/D layout: row = (l>>4)*4 + r, col = l&15.
    #pragma unroll
    for (int rt = 0; rt < 8; ++rt) {
        #pragma unroll
        for (int r = 0; r < 4; ++r) {
            float s = expacc[rt][r];
            s += __shfl_xor(s, 1); s += __shfl_xor(s, 2);
            s += __shfl_xor(s, 4); s += __shfl_xor(s, 8);
            if ((l & 15) == 0) sums[w][rt * 16 + (l >> 4) * 4 + r] = s;
        }
    }
    __syncthreads();

    float term = 0.f;
    if (tid < 128) {
        float S = sums[0][tid] + sums[1][tid] + sums[2][tid] + sums[3][tid];
        // shift m=2; sim11 diag contributes exp(0)=1, excluded in closed form
        term = 2.0f + __logf(S - 1.0f) - pos[g * GSIZE + rowBase + tid];
    }
    #pragma unroll
    for (int m = 1; m < 64; m <<= 1) term += __shfl_xor(term, m);
    if (l == 0) red[w] = term;   // waves 2,3 contribute 0
    __syncthreads();
    if (tid == 0) partials[n] = red[0] + red[1] + red[2] + red[3];
}

// Kernel 3: deterministic 512 -> 1 reduce, mean over nodes.
__global__ __launch_bounds__(256) void final_reduce_k(
    const float* __restrict__ partials, float* __restrict__ out)
{
    int tid = threadIdx.x;
    float s = partials[tid] + partials[tid + 256];
    #pragma unroll
    for (int m = 1; m < 64; m <<= 1) s += __shfl_xor(s, m);
    __shared__ float red[4];
    if ((tid & 63) == 0) red[tid >> 6] = s;
    __syncthreads();
    if (tid == 0) out[0] = (red[0] + red[1] + red[2] + red[3]) * (1.0f / N_NODES);
}

extern "C" void kernel_launch(void* const* d_in, const int* in_sizes, int n_in,
                              void* d_out, int out_size, void* d_ws, size_t ws_size,
                              hipStream_t stream)
{
    const float* z1 = (const float*)d_in[0];
    const float* z2 = (const float*)d_in[1];
    char* ws = (char*)d_ws;
    unsigned short* z1n = (unsigned short*)ws;                       // 8 MB
    unsigned short* z2n = (unsigned short*)(ws + 8388608);           // 8 MB
    float* pos          = (float*)(ws + 16777216);                   // 256 KB
    float* partials     = (float*)(ws + 17039360);                   // 2 KB

    normalize_k<<<dim3(N_NODES / 16), dim3(256), 0, stream>>>(z1, z2, z1n, z2n, pos);
    grace_main_k<<<dim3(NUM_G * 8), dim3(256), 0, stream>>>(z1n, z2n, pos, partials);
    final_reduce_k<<<dim3(1), dim3(256), 0, stream>>>(partials, (float*)d_out);
}